// Round 1
// 2010.451 us; speedup vs baseline: 1.1542x; 1.1542x over previous
//
#include <hip/hip_runtime.h>
#include <hip/hip_bf16.h>
#include <stdint.h>
#include <stddef.h>

// Problem: out[M,N] = (x[M,K] @ W_q[N,K]^T) / scales[N] + bias[N]
// M = B*S = 8192, K = 4096, N = 16384. x f32, W_q int32 (int8 range).
#define M_DIM 8192
#define K_DIM 4096
#define N_DIM 16384
#define NT (K_DIM / 64)  // 64 K-tiles of BK=64

typedef __attribute__((ext_vector_type(8))) short short8;
typedef __attribute__((ext_vector_type(4))) float f32x4;

// f32 -> bf16 round-to-nearest-even. Exact for int8-range integers.
__device__ __forceinline__ unsigned short f2bf(float f) {
    union { float f; uint32_t u; } c; c.f = f;
    uint32_t u = c.u;
    return (unsigned short)((u + 0x7FFFu + ((u >> 16) & 1u)) >> 16);
}

// ---------------- conversion kernels (path A) ----------------

__global__ __launch_bounds__(256) void conv_x_kernel(const float* __restrict__ x,
                                                     unsigned short* __restrict__ out) {
    size_t i = ((size_t)blockIdx.x * 256 + threadIdx.x) * 8;
    const float4* p = (const float4*)(x + i);
    float4 u = p[0], v = p[1];
    short8 h;
    h[0] = (short)f2bf(u.x); h[1] = (short)f2bf(u.y);
    h[2] = (short)f2bf(u.z); h[3] = (short)f2bf(u.w);
    h[4] = (short)f2bf(v.x); h[5] = (short)f2bf(v.y);
    h[6] = (short)f2bf(v.z); h[7] = (short)f2bf(v.w);
    *(short8*)(out + i) = h;
}

__global__ __launch_bounds__(256) void conv_w_kernel(const int* __restrict__ w,
                                                     unsigned short* __restrict__ out) {
    size_t i = ((size_t)blockIdx.x * 256 + threadIdx.x) * 8;
    const int4* p = (const int4*)(w + i);
    int4 u = p[0], v = p[1];
    short8 h;
    h[0] = (short)f2bf((float)u.x); h[1] = (short)f2bf((float)u.y);
    h[2] = (short)f2bf((float)u.z); h[3] = (short)f2bf((float)u.w);
    h[4] = (short)f2bf((float)v.x); h[5] = (short)f2bf((float)v.y);
    h[6] = (short)f2bf((float)v.z); h[7] = (short)f2bf((float)v.w);
    *(short8*)(out + i) = h;
}

// ---------------- async global->LDS helper ----------------

__device__ __forceinline__ void gld_lds16(const void* g, void* l) {
    __builtin_amdgcn_global_load_lds(
        (__attribute__((address_space(1))) void*)(g),
        (__attribute__((address_space(3))) void*)(l),
        16, 0, 0);
}

// Stage one half-tile (128 rows x 64 cols bf16 = 16 KB) into LDS.
// LDS destination is LINEAR (gld_lds requires uniform-base + lane*16);
// the XOR swizzle (chunk ^= row&7) is applied to the GLOBAL SOURCE column
// (rule #21: inverse-swizzled source + swizzled read = both-sides).
__device__ __forceinline__ void stage_half(const unsigned short* __restrict__ src,
                                           unsigned short* lbase, int tid) {
#pragma unroll
    for (int i = 0; i < 2; ++i) {
        int c = tid + i * 512;                 // 0..1023 16B chunks
        int row = c >> 3;                      // 0..127
        int col = ((c & 7) ^ (row & 7)) << 3;  // swizzled source column (bf16 units)
        gld_lds16(src + (size_t)row * K_DIM + col, (char*)lbase + (size_t)c * 16);
    }
}

// Swizzled ds_read_b128 of one MFMA fragment. r = row in 256-row tile,
// kc = k-chunk 0..7 (8 bf16 per chunk). Conflict-free: the 8 rows of each
// 8-row stripe map to 8 distinct 16B bank slots.
__device__ __forceinline__ short8 lds_frag(const unsigned short* base, int r, int kc) {
    return *(const short8*)(base + r * 64 + ((kc ^ (r & 7)) << 3));
}

#define BAR()                                \
    do {                                     \
        asm volatile("" ::: "memory");       \
        __builtin_amdgcn_s_barrier();        \
        asm volatile("" ::: "memory");       \
    } while (0)
#define LGKM0() asm volatile("s_waitcnt lgkmcnt(0)" ::: "memory")

// ---------------- main GEMM: 256x256 tile, 8-phase counted-vmcnt pipeline ----------------
// 512 threads = 8 waves (2 M x 4 N), per-wave output 128x64.
// LDS: 2 x (A 256x64 + B 256x64) bf16 = 128 KiB double buffer.
// Per K-tile: 4 phases, each {ds_read subtile || stage 1 half-tile -> barrier
//   -> lgkmcnt(0) -> setprio(1) -> 16 MFMA -> setprio(0) -> barrier}.
// Staging: A halves 1 tile ahead (phases 0,1), B halves 2 tiles ahead
// (phases 2,3 -> same buffer index, into regions freed at phases 1,2).
// vmcnt(4) once per tile leaves exactly the 2 newest half-tiles in flight.

__global__ __launch_bounds__(512, 2) void gemm_a_kernel(
    const unsigned short* __restrict__ A,   // [M,K] bf16 (x)
    const unsigned short* __restrict__ Bm,  // [N,K] bf16 (W)
    const float* __restrict__ scales,
    const float* __restrict__ bias,
    float* __restrict__ C) {
    __shared__ unsigned short As[2][256 * 64];
    __shared__ unsigned short Bs[2][256 * 64];

    const int tid = threadIdx.x;
    const int lane = tid & 63;
    const int wv = tid >> 6;
    const int wm = (wv & 1) * 128;   // wave M offset in tile
    const int wn = (wv >> 1) * 64;   // wave N offset in tile
    const int lm = lane & 15;
    const int kseg = lane >> 4;      // 0..3

    // XCD-aware remap (2048 blocks, 2048 % 8 == 0 -> simple swizzle bijective).
    // XCD x owns M-tile band [4x, 4x+4) x all 64 N-tiles; resident window on
    // one XCD (32 CUs, 1 block/CU) is a 4M x 8N supertile -> L2 panel sharing.
    const int bid = blockIdx.x;
    const int tm = (bid & 7) * 4 + ((bid >> 3) & 3);  // 0..31
    const int tn = bid >> 5;                          // 0..63
    const int m0 = tm * 256, n0 = tn * 256;

    const unsigned short* Ab = A + (size_t)m0 * K_DIM;
    const unsigned short* Bb = Bm + (size_t)n0 * K_DIM;

    f32x4 acc[8][4] = {};
    short8 a[4][2], bA[2][2], bB[2][2];

    // Prologue: stage A(0) both halves, B(0) both halves, B(1) both halves.
    stage_half(Ab,                            &As[0][0],        tid);
    stage_half(Ab + (size_t)128 * K_DIM,      &As[0][128 * 64], tid);
    stage_half(Bb,                            &Bs[0][0],        tid);
    stage_half(Bb + (size_t)128 * K_DIM,      &Bs[0][128 * 64], tid);
    stage_half(Bb + 64,                       &Bs[1][0],        tid);
    stage_half(Bb + (size_t)128 * K_DIM + 64, &Bs[1][128 * 64], tid);
    asm volatile("s_waitcnt vmcnt(4)" ::: "memory");  // A(0)+B(0) done; B(1) in flight
    BAR();

    for (int t = 0; t < NT; ++t) {
        const int cb = t & 1;
        const unsigned short* Ac = &As[cb][0];
        const unsigned short* Bc = &Bs[cb][0];
        unsigned short* Anx = &As[cb ^ 1][0];  // tile t+1 -> other buffer
        unsigned short* Bnx = &Bs[cb][0];      // tile t+2 -> same buffer index
        // Clamped tail: re-stage last tile's data into already-freed regions
        // (never read again) to keep the vmcnt ledger uniform.
        const size_t kA = (size_t)((t + 1 < NT) ? t + 1 : NT - 1) * 64;
        const size_t kB = (size_t)((t + 2 < NT) ? t + 2 : NT - 1) * 64;

        // ---- phase 0: quadrant (M 0-63, N 0-31). 12 ds_reads. stage A0(t+1).
#pragma unroll
        for (int im = 0; im < 4; ++im)
#pragma unroll
            for (int kx = 0; kx < 2; ++kx)
                a[im][kx] = lds_frag(Ac, wm + im * 16 + lm, kx * 4 + kseg);
#pragma unroll
        for (int jn = 0; jn < 2; ++jn)
#pragma unroll
            for (int kx = 0; kx < 2; ++kx)
                bA[jn][kx] = lds_frag(Bc, wn + jn * 16 + lm, kx * 4 + kseg);
        stage_half(Ab + kA, Anx, tid);
        BAR();
        LGKM0();
        __builtin_amdgcn_s_setprio(1);
#pragma unroll
        for (int im = 0; im < 4; ++im)
#pragma unroll
            for (int jn = 0; jn < 2; ++jn)
#pragma unroll
                for (int kx = 0; kx < 2; ++kx)
                    acc[im][jn] = __builtin_amdgcn_mfma_f32_16x16x32_bf16(
                        a[im][kx], bA[jn][kx], acc[im][jn], 0, 0, 0);
        __builtin_amdgcn_s_setprio(0);
        BAR();

        // ---- phase 1: quadrant (M 0-63, N 32-63). 4 ds_reads. stage A1(t+1).
#pragma unroll
        for (int jn = 0; jn < 2; ++jn)
#pragma unroll
            for (int kx = 0; kx < 2; ++kx)
                bB[jn][kx] = lds_frag(Bc, wn + (jn + 2) * 16 + lm, kx * 4 + kseg);
        stage_half(Ab + (size_t)128 * K_DIM + kA, Anx + 128 * 64, tid);
        BAR();
        LGKM0();
        __builtin_amdgcn_s_setprio(1);
#pragma unroll
        for (int im = 0; im < 4; ++im)
#pragma unroll
            for (int jn = 0; jn < 2; ++jn)
#pragma unroll
                for (int kx = 0; kx < 2; ++kx)
                    acc[im][jn + 2] = __builtin_amdgcn_mfma_f32_16x16x32_bf16(
                        a[im][kx], bB[jn][kx], acc[im][jn + 2], 0, 0, 0);
        __builtin_amdgcn_s_setprio(0);
        BAR();

        // ---- phase 2: quadrant (M 64-127, N 32-63). 8 ds_reads. stage B0(t+2)
        //      into region freed after phase 1 (B rows 0-127 fully read).
#pragma unroll
        for (int im = 0; im < 4; ++im)
#pragma unroll
            for (int kx = 0; kx < 2; ++kx)
                a[im][kx] = lds_frag(Ac, wm + (im + 4) * 16 + lm, kx * 4 + kseg);
        stage_half(Bb + kB, Bnx, tid);
        BAR();
        LGKM0();
        __builtin_amdgcn_s_setprio(1);
#pragma unroll
        for (int im = 0; im < 4; ++im)
#pragma unroll
            for (int jn = 0; jn < 2; ++jn)
#pragma unroll
                for (int kx = 0; kx < 2; ++kx)
                    acc[im + 4][jn + 2] = __builtin_amdgcn_mfma_f32_16x16x32_bf16(
                        a[im][kx], bB[jn][kx], acc[im + 4][jn + 2], 0, 0, 0);
        __builtin_amdgcn_s_setprio(0);
        BAR();

        // ---- phase 3: quadrant (M 64-127, N 0-31). 0 ds_reads (bA held in
        //      regs since phase 0). stage B1(t+2). Counted vmcnt at tile end.
        stage_half(Bb + (size_t)128 * K_DIM + kB, Bnx + 128 * 64, tid);
        BAR();
        LGKM0();
        __builtin_amdgcn_s_setprio(1);
#pragma unroll
        for (int im = 0; im < 4; ++im)
#pragma unroll
            for (int jn = 0; jn < 2; ++jn)
#pragma unroll
                for (int kx = 0; kx < 2; ++kx)
                    acc[im + 4][jn] = __builtin_amdgcn_mfma_f32_16x16x32_bf16(
                        a[im][kx], bA[jn][kx], acc[im + 4][jn], 0, 0, 0);
        __builtin_amdgcn_s_setprio(0);
        // Leave only the 2 newest half-tiles (this tile's B0/B1 prefetch, 4
        // loads) in flight: guarantees A(t+1) and B(t+1) are resident.
        asm volatile("s_waitcnt vmcnt(4)" ::: "memory");
        BAR();
    }

    asm volatile("s_waitcnt vmcnt(0)" ::: "memory");  // drain tail garbage loads
    BAR();

    // Epilogue: out = acc / scale[col] + bias[col]
    // C/D layout (16x16x32): col = lane&15, row = (lane>>4)*4 + reg
#pragma unroll
    for (int jn = 0; jn < 4; ++jn) {
        const int coln = n0 + wn + jn * 16 + lm;
        const float inv = 1.0f / scales[coln];
        const float bb = bias[coln];
#pragma unroll
        for (int im = 0; im < 8; ++im) {
            const int r0 = m0 + wm + im * 16 + kseg * 4;
#pragma unroll
            for (int r = 0; r < 4; ++r)
                C[(size_t)(r0 + r) * N_DIM + coln] = acc[im][jn][r] * inv + bb;
        }
    }
}

// ---------------- fallback GEMM (path B: inline conversion, no workspace) ----------------

__global__ __launch_bounds__(256) void gemm_b_kernel(
    const float* __restrict__ X,   // [M,K] f32
    const int* __restrict__ W,     // [N,K] int32
    const float* __restrict__ scales,
    const float* __restrict__ bias,
    float* __restrict__ C) {
    __shared__ unsigned short As[128 * 64];
    __shared__ unsigned short Bs[128 * 64];

    const int tid = threadIdx.x;
    const int m0 = blockIdx.y * 128;
    const int n0 = blockIdx.x * 128;
    const int lane = tid & 63;
    const int wv = tid >> 6;
    const int wm = (wv & 1) * 64;
    const int wn = (wv >> 1) * 64;
    const int lm = lane & 15;
    const int lk = (lane >> 4) * 8;

    f32x4 acc[4][4] = {};

    for (int kt = 0; kt < K_DIM / 64; ++kt) {
        const int k0 = kt * 64;
#pragma unroll
        for (int i = 0; i < 4; ++i) {
            int c = tid + i * 256;
            int row = c >> 3, col = (c & 7) * 8;
            const float* p = X + (size_t)(m0 + row) * K_DIM + k0 + col;
            float4 u = *(const float4*)p;
            float4 v = *(const float4*)(p + 4);
            short8 h;
            h[0] = (short)f2bf(u.x); h[1] = (short)f2bf(u.y);
            h[2] = (short)f2bf(u.z); h[3] = (short)f2bf(u.w);
            h[4] = (short)f2bf(v.x); h[5] = (short)f2bf(v.y);
            h[6] = (short)f2bf(v.z); h[7] = (short)f2bf(v.w);
            *(short8*)&As[(size_t)c * 8] = h;
        }
#pragma unroll
        for (int i = 0; i < 4; ++i) {
            int c = tid + i * 256;
            int row = c >> 3, col = (c & 7) * 8;
            const int* p = W + (size_t)(n0 + row) * K_DIM + k0 + col;
            int4 u = *(const int4*)p;
            int4 v = *(const int4*)(p + 4);
            short8 h;
            h[0] = (short)f2bf((float)u.x); h[1] = (short)f2bf((float)u.y);
            h[2] = (short)f2bf((float)u.z); h[3] = (short)f2bf((float)u.w);
            h[4] = (short)f2bf((float)v.x); h[5] = (short)f2bf((float)v.y);
            h[6] = (short)f2bf((float)v.z); h[7] = (short)f2bf((float)v.w);
            *(short8*)&Bs[(size_t)c * 8] = h;
        }
        __syncthreads();

#pragma unroll
        for (int kk = 0; kk < 64; kk += 32) {
            short8 af[4], bfr[4];
#pragma unroll
            for (int im = 0; im < 4; ++im)
                af[im] = *(const short8*)&As[(wm + im * 16 + lm) * 64 + kk + lk];
#pragma unroll
            for (int jn = 0; jn < 4; ++jn)
                bfr[jn] = *(const short8*)&Bs[(wn + jn * 16 + lm) * 64 + kk + lk];
#pragma unroll
            for (int im = 0; im < 4; ++im)
#pragma unroll
                for (int jn = 0; jn < 4; ++jn)
                    acc[im][jn] = __builtin_amdgcn_mfma_f32_16x16x32_bf16(
                        af[im], bfr[jn], acc[im][jn], 0, 0, 0);
        }
        __syncthreads();
    }

#pragma unroll
    for (int jn = 0; jn < 4; ++jn) {
        const int col = n0 + wn + jn * 16 + lm;
        const float inv = 1.0f / scales[col];
        const float bb = bias[col];
#pragma unroll
        for (int im = 0; im < 4; ++im) {
            const int r0 = m0 + wm + im * 16 + (lane >> 4) * 4;
#pragma unroll
            for (int r = 0; r < 4; ++r)
                C[(size_t)(r0 + r) * N_DIM + col] = acc[im][jn][r] * inv + bb;
        }
    }
}

// ---------------- launch ----------------

extern "C" void kernel_launch(void* const* d_in, const int* in_sizes, int n_in,
                              void* d_out, int out_size, void* d_ws, size_t ws_size,
                              hipStream_t stream) {
    const float* x      = (const float*)d_in[0];  // [8192, 4096] f32
    const int*   wq     = (const int*)d_in[1];    // [16384, 4096] int32
    const float* scales = (const float*)d_in[2];  // [16384]
    const float* bias   = (const float*)d_in[3];  // [16384]
    float* out = (float*)d_out;                   // [8192, 16384] f32

    const size_t x_elems = (size_t)M_DIM * K_DIM;   // 33.5M
    const size_t w_elems = (size_t)N_DIM * K_DIM;   // 67.1M
    const size_t need = (x_elems + w_elems) * sizeof(unsigned short); // 192 MB

    if (ws_size >= need) {
        unsigned short* xbf = (unsigned short*)d_ws;
        unsigned short* wbf = xbf + x_elems;
        conv_x_kernel<<<(int)(x_elems / (256 * 8)), 256, 0, stream>>>(x, xbf);
        conv_w_kernel<<<(int)(w_elems / (256 * 8)), 256, 0, stream>>>(wq, wbf);
        const int nblocks = (M_DIM / 256) * (N_DIM / 256);  // 32 * 64 = 2048
        gemm_a_kernel<<<nblocks, 512, 0, stream>>>(xbf, wbf, scales, bias, out);
    } else {
        dim3 grid(N_DIM / 128, M_DIM / 128);
        gemm_b_kernel<<<grid, 256, 0, stream>>>(x, wq, scales, bias, out);
    }
}